// Round 9
// baseline (141.574 us; speedup 1.0000x reference)
//
#include <hip/hip_runtime.h>
#include <hip/hip_bf16.h>

typedef _Float16 half2v __attribute__((ext_vector_type(2)));
typedef _Float16 half8  __attribute__((ext_vector_type(8)));
typedef __attribute__((ext_vector_type(4))) float floatx4;
typedef __attribute__((ext_vector_type(4))) unsigned int uintx4;

// Compiler scheduling fence: memory ops may not cross (pins load-issue order;
// ALU schedules freely around the pinned load skeleton).
#define SCHED_FENCE() asm volatile("" ::: "memory")

__device__ __forceinline__ half2v h2(float v) {
  return (half2v){(_Float16)v, (_Float16)v};
}

// tanh(x0),tanh(x1) -> packed-f16 Legendre P1..P8 for BOTH rows (R7-verified).
// fa0 = low halves (row0), fa1 = high halves (row1). ~35 VALU total.
__device__ __forceinline__ void legendre2_f16(float xv0, float xv1,
                                              half8* fa0, half8* fa1) {
  float e0 = __builtin_amdgcn_exp2f(xv0 * 2.885390081777927f); // 2*log2(e)
  float t0 = 1.0f - 2.0f * __builtin_amdgcn_rcpf(e0 + 1.0f);
  float e1 = __builtin_amdgcn_exp2f(xv1 * 2.885390081777927f);
  float t1 = 1.0f - 2.0f * __builtin_amdgcn_rcpf(e1 + 1.0f);
  half2v t;
  { auto tt = __builtin_amdgcn_cvt_pkrtz(t0, t1); __builtin_memcpy(&t, &tt, 4); }
  half2v p1 = t;
  half2v u2 = t * p1, w2 = u2 - h2(1.0f);  half2v p2 = h2(0.5f)      * w2 + u2;
  half2v u3 = t * p2, w3 = u3 - p1;        half2v p3 = h2(2.0f/3.0f) * w3 + u3;
  half2v u4 = t * p3, w4 = u4 - p2;        half2v p4 = h2(0.75f)     * w4 + u4;
  half2v u5 = t * p4, w5 = u5 - p3;        half2v p5 = h2(0.8f)      * w5 + u5;
  half2v u6 = t * p5, w6 = u6 - p4;        half2v p6 = h2(5.0f/6.0f) * w6 + u6;
  half2v u7 = t * p6, w7 = u7 - p5;        half2v p7 = h2(6.0f/7.0f) * w7 + u7;
  half2v u8 = t * p7, w8 = u8 - p6;        half2v p8 = h2(7.0f/8.0f) * w8 + u8;
  unsigned P[8];
  __builtin_memcpy(&P[0], &p1, 4); __builtin_memcpy(&P[1], &p2, 4);
  __builtin_memcpy(&P[2], &p3, 4); __builtin_memcpy(&P[3], &p4, 4);
  __builtin_memcpy(&P[4], &p5, 4); __builtin_memcpy(&P[5], &p6, 4);
  __builtin_memcpy(&P[6], &p7, 4); __builtin_memcpy(&P[7], &p8, 4);
  union { unsigned u[4]; half8 h; } a0, a1;
#pragma unroll
  for (int j = 0; j < 4; ++j) {
    a0.u[j] = __builtin_amdgcn_perm(P[2*j+1], P[2*j], 0x05040100u); // low halves
    a1.u[j] = __builtin_amdgcn_perm(P[2*j+1], P[2*j], 0x07060302u); // high halves
  }
  *fa0 = a0.h;
  *fa1 = a1.h;
}

// ---- kernel 1: c_basis fp32 -> f16, transposed to ws[i][o][d] (256 KB) ----
__global__ void conv_kernel(const float* __restrict__ cb, _Float16* __restrict__ ws) {
  int t = blockIdx.x * 128 + threadIdx.x;   // 0..16383 = (o,i)
  int o = t >> 8;
  int i = t & 255;
  const floatx4* s = (const floatx4*)(cb + ((size_t)o * 256 + i) * 8);
  floatx4 v0 = s[0], v1 = s[1];
  union { _Float16 h[8]; uintx4 u; } w;
  w.h[0] = (_Float16)v0.x; w.h[1] = (_Float16)v0.y;
  w.h[2] = (_Float16)v0.z; w.h[3] = (_Float16)v0.w;
  w.h[4] = (_Float16)v1.x; w.h[5] = (_Float16)v1.y;
  w.h[6] = (_Float16)v1.z; w.h[7] = (_Float16)v1.w;
  *(uintx4*)(ws + (size_t)i * 512 + o * 8) = w.u;
}

// ---- kernel 2: barrier-free K-split, direct loads, fence-pinned pipeline ----
// 128 thr = 2 waves over the SAME 32 rows; wave w handles i in [128w,128w+128)
// (32 K-steps of K=32). Grid 2048 -> 8 blocks/CU, 4 waves/SIMD. No K-loop
// barriers; one __syncthreads for the epilogue cross-wave reduction.
#define ITERS 32

__global__ __launch_bounds__(128, 4) void kan_kernel(
    const float* __restrict__ x, const _Float16* __restrict__ ws,
    const float* __restrict__ bias, float* __restrict__ y) {
  __shared__ floatx4 red[8 * 64];   // 8 KB epilogue reduction buffer

  const int tid  = threadIdx.x;
  const int wid  = tid >> 6;    // 0..1 = K-half
  const int lane = tid & 63;
  const int m    = lane & 15;
  const int q    = lane >> 4;
  const int row_block = blockIdx.x * 32;

  floatx4 acc[2][4];
#pragma unroll
  for (int a = 0; a < 2; ++a)
#pragma unroll
    for (int nt = 0; nt < 4; ++nt) acc[a][nt] = (floatx4){0.f, 0.f, 0.f, 0.f};

  // lane's A-frag at local step s covers i = wid*128 + s*4 + q, rows m / m+16
  const float* xp0 = x + (size_t)(row_block + m) * 256 + wid * 128 + q; // +4/step
  const float* xp1 = xp0 + 16 * 256;
  // B-frag shorts: wid*65536 + (s*4)*512 + q*512 + nt*128 + m*8
  const _Float16* bp = ws + (size_t)wid * 65536 + q * 512 + m * 8;

  // rings: x depth 2 (mod-4), B depth 1 (mod-2)
  float xq0[4], xq1[4];
  half8 fbq[2][4];
  xq0[0] = xp0[0]; xq1[0] = xp1[0];
  xq0[1] = xp0[4]; xq1[1] = xp1[4];
#pragma unroll
  for (int nt = 0; nt < 4; ++nt) fbq[0][nt] = *(const half8*)(bp + nt * 128);
  SCHED_FENCE();

#pragma unroll
  for (int s = 0; s < ITERS; ++s) {
    // issue prefetches for s+2 (x) and s+1 (B); fence pins them before compute
    if (s + 2 < ITERS) {
      xq0[(s + 2) & 3] = xp0[(s + 2) * 4];
      xq1[(s + 2) & 3] = xp1[(s + 2) * 4];
    }
    if (s + 1 < ITERS) {
#pragma unroll
      for (int nt = 0; nt < 4; ++nt)
        fbq[(s + 1) & 1][nt] = *(const half8*)(bp + (size_t)(s + 1) * 2048 + nt * 128);
    }
    SCHED_FENCE();

    half8 fa0, fa1;
    legendre2_f16(xq0[s & 3], xq1[s & 3], &fa0, &fa1);
    const int b = s & 1;
    acc[0][0] = __builtin_amdgcn_mfma_f32_16x16x32_f16(fa0, fbq[b][0], acc[0][0], 0, 0, 0);
    acc[1][0] = __builtin_amdgcn_mfma_f32_16x16x32_f16(fa1, fbq[b][0], acc[1][0], 0, 0, 0);
    acc[0][1] = __builtin_amdgcn_mfma_f32_16x16x32_f16(fa0, fbq[b][1], acc[0][1], 0, 0, 0);
    acc[1][1] = __builtin_amdgcn_mfma_f32_16x16x32_f16(fa1, fbq[b][1], acc[1][1], 0, 0, 0);
    acc[0][2] = __builtin_amdgcn_mfma_f32_16x16x32_f16(fa0, fbq[b][2], acc[0][2], 0, 0, 0);
    acc[1][2] = __builtin_amdgcn_mfma_f32_16x16x32_f16(fa1, fbq[b][2], acc[1][2], 0, 0, 0);
    acc[0][3] = __builtin_amdgcn_mfma_f32_16x16x32_f16(fa0, fbq[b][3], acc[0][3], 0, 0, 0);
    acc[1][3] = __builtin_amdgcn_mfma_f32_16x16x32_f16(fa1, fbq[b][3], acc[1][3], 0, 0, 0);
  }

  // ---- cross-wave K-reduction + epilogue (R5-verified) ----
  if (wid == 1) {
#pragma unroll
    for (int a = 0; a < 2; ++a)
#pragma unroll
      for (int nt = 0; nt < 4; ++nt)
        red[(a * 4 + nt) * 64 + lane] = acc[a][nt];
  }
  __syncthreads();
  if (wid == 0) {
    float bv[4];
#pragma unroll
    for (int nt = 0; nt < 4; ++nt) bv[nt] = bias[nt * 16 + m];
#pragma unroll
    for (int a = 0; a < 2; ++a) {
      int gr0 = row_block + a * 16 + q * 4;   // D[row=q*4+reg][col=m]
#pragma unroll
      for (int nt = 0; nt < 4; ++nt) {
        floatx4 p = red[(a * 4 + nt) * 64 + lane];
#pragma unroll
        for (int r = 0; r < 4; ++r) {
          y[(size_t)(gr0 + r) * 64 + nt * 16 + m] = acc[a][nt][r] + p[r] + bv[nt];
        }
      }
    }
  }
}

extern "C" void kernel_launch(void* const* d_in, const int* in_sizes, int n_in,
                              void* d_out, int out_size, void* d_ws, size_t ws_size,
                              hipStream_t stream) {
  const float* x    = (const float*)d_in[0];
  const float* cb   = (const float*)d_in[1];
  const float* bias = (const float*)d_in[2];
  float* y = (float*)d_out;
  _Float16* ws = (_Float16*)d_ws;
  int batch = in_sizes[0] / 256;  // 65536
  hipLaunchKernelGGL(conv_kernel, dim3(128), dim3(128), 0, stream, cb, ws);
  hipLaunchKernelGGL(kan_kernel, dim3(batch / 32), dim3(128), 0, stream, x, ws, bias, y);
}